// Round 5
// baseline (132.632 us; speedup 1.0000x reference)
//
#include <hip/hip_runtime.h>

// Fused 2-level inverse Haar DWT (UnPatcher, PATCH_SIZE=4) — long-burst LDS version.
// Input  x:   [8, 256, 96, 96]  fp32
// Output out: [8, 16, 384, 384] fp32
//
// v7 post-mortem: ideal load/store instruction shapes were only +6% over scalar
// baseline -> instruction path, MLP, occupancy all ruled out. Remaining theory:
// DRAM row locality. v7 read streams were 1KB bursts hopping between 16 planes
// 576KB apart (~73k distinct 1KB regions device-wide). v8 lengthens each stream
// burst to 4KB (CHUNK=1024) and makes the per-block output a single ~64KB
// contiguous region. Staging uses width-16 global_load_lds (async DMA, linear
// lane order == the wave-uniform-base + lane*16B contract; no VGPR roundtrip).
//
//   load:  16 streams x 4KB per block, 64 async global_load_lds_dwordx4 wave-ops
//   LDS:   [16 ch][1024 qp] fp32 = 64 KB (dynamic), 2 blocks/CU
//   comp:  thread t, u=0..3: qp = qp0 + 256u + t; 16 lane-consecutive ds_reads
//          (conflict-free), 2-level +/-1 butterfly (per-level scale 2*S*S == 1)
//   store: 4 float4 rows per (t,u): contiguous 1KB wave stores (ideal WRITE_SIZE,
//          verified in v5/v7)

#define B_     8
#define CIN    256
#define G_     16
#define PLANE  9216   // 96*96
#define W_     96
#define OW     384
#define CHUNK  1024
#define NCHUNK (PLANE / CHUNK)   // 9

typedef float f4 __attribute__((ext_vector_type(4)));

extern __shared__ float lds[];   // 16 * 1024 floats = 64 KB

__global__ __launch_bounds__(256) void idwt2_fused_v8(const float* __restrict__ x,
                                                      float* __restrict__ out) {
    const int bid   = blockIdx.x;
    const int chunk = bid % NCHUNK;
    const int t1    = bid / NCHUNK;
    const int g     = t1 % G_;
    const int b     = t1 / G_;
    const int qp0   = chunk * CHUNK;

    const int t    = threadIdx.x;
    const int w    = t >> 6;   // wave id 0..3
    const int lane = t & 63;

    // ---- Load phase: 64 (j, seg) 1KB wave-DMAs; wave w takes pi = 16w..16w+15.
    // Stream j = channel tap (ch = g + 16j), seg = 256-qp segment within chunk.
    const float* xb = x + (size_t)b * CIN * PLANE + (size_t)qp0;
#pragma unroll
    for (int i = 0; i < 16; ++i) {
        const int pi  = 16 * w + i;
        const int j   = pi >> 2;        // 0..15
        const int seg = pi & 3;         // 0..3
        const int ch  = g + 16 * j;
        const float* src = xb + (size_t)ch * PLANE + seg * 256 + 4 * lane;
        float* dst = &lds[j * CHUNK + seg * 256];  // + lane*16B by HW
        __builtin_amdgcn_global_load_lds(
            (const __attribute__((address_space(1))) void*)src,
            (__attribute__((address_space(3))) void*)dst,
            16, 0, 0);
    }
    __syncthreads();  // compiler emits vmcnt(0) drain before barrier

    // ---- Compute + store: 4 qp per thread (stride 256 keeps stores coalesced).
#pragma unroll
    for (int u = 0; u < 4; ++u) {
        const int tq = 256 * u + t;

        float vv[16];
#pragma unroll
        for (int j = 0; j < 16; ++j) {
            vv[j] = lds[j * CHUNK + tq];   // lane-consecutive -> conflict-free
        }

        // Level 1 (inner butterfly): v[k][m] = vv[k + 4m], ch = g + 16k + 64m
        float tt[4][2][2];
#pragma unroll
        for (int k = 0; k < 4; ++k) {
            float u0 = vv[k + 0] + vv[k + 4];
            float u1 = vv[k + 0] - vv[k + 4];
            float u2 = vv[k + 8] + vv[k + 12];
            float u3 = vv[k + 8] - vv[k + 12];
            tt[k][0][0] = u0 + u2;
            tt[k][0][1] = u0 - u2;
            tt[k][1][0] = u1 + u3;
            tt[k][1][1] = u1 - u3;
        }

        // Level 2 (outer butterfly) -> 4x4 output tile
        float rowv[4][4];
#pragma unroll
        for (int dh = 0; dh < 2; ++dh) {
#pragma unroll
            for (int dw = 0; dw < 2; ++dw) {
                float a0 = tt[0][dh][dw] + tt[1][dh][dw];
                float a1 = tt[0][dh][dw] - tt[1][dh][dw];
                float a2 = tt[2][dh][dw] + tt[3][dh][dw];
                float a3 = tt[2][dh][dw] - tt[3][dh][dw];
                rowv[2 * dh + 0][2 * dw + 0] = a0 + a2;
                rowv[2 * dh + 0][2 * dw + 1] = a0 - a2;
                rowv[2 * dh + 1][2 * dw + 0] = a1 + a3;
                rowv[2 * dh + 1][2 * dw + 1] = a1 - a3;
            }
        }

        const int qp = qp0 + tq;
        const int p  = qp / W_;
        const int q  = qp % W_;
        float* obase = out + ((size_t)(b * G_ + g) * OW + 4 * (size_t)p) * OW
                       + 4 * (size_t)q;
#pragma unroll
        for (int r = 0; r < 4; ++r) {
            f4 s;
            s.x = rowv[r][0];
            s.y = rowv[r][1];
            s.z = rowv[r][2];
            s.w = rowv[r][3];
            *reinterpret_cast<f4*>(obase + (size_t)r * OW) = s;
        }
    }
}

extern "C" void kernel_launch(void* const* d_in, const int* in_sizes, int n_in,
                              void* d_out, int out_size, void* d_ws, size_t ws_size,
                              hipStream_t stream) {
    const float* x = (const float*)d_in[0];
    float* out = (float*)d_out;
    const int grid = B_ * G_ * NCHUNK;        // 1152 blocks x 256 threads
    const size_t lds_bytes = 16 * CHUNK * sizeof(float);  // 65536
    idwt2_fused_v8<<<grid, 256, lds_bytes, stream>>>(x, out);
}

// Round 6
// 130.200 us; speedup vs baseline: 1.0187x; 1.0187x over previous
//
#include <hip/hip_runtime.h>

// Fused 2-level inverse Haar DWT (UnPatcher, PATCH_SIZE=4) — v7 + XCD-affine swizzle.
// Input  x:   [8, 256, 96, 96]  fp32
// Output out: [8, 16, 384, 384] fp32
//
// v8 post-mortem: 4KB bursts + DMA staging were WORSE (46.8us vs v7's 41.4us);
// burst length ruled out. Five diverse structures all land 41-47us at ideal
// line-level traffic -> not DRAM-, L2-, issue-, or occupancy-limited.
// Last untested lever: XCD topology. Reads are ~half warm (FETCH 37MB < 75.5MB
// input) from the harness fill; those dirty lines live in other XCDs' L2s under
// default round-robin dispatch (every plane interleaved across 8 XCDs at 1KB).
// v9 = v7 exactly, plus a bijective block swizzle giving each XCD one batch b:
// 4608 blocks = 8 XCDs x 576; logical_bid = (hw%8)*576 + hw/8. Each XCD then
// reads/writes a private contiguous 9.4MB region; its 32 CUs sweep a ~1.2MB
// window that fits the 4MB XCD L2.
//
//   load:  per block, stage [16 ch][256 qp] (16KB LDS) with dwordx4 loads —
//          each instruction a contiguous 1KB wave run.
//   comp:  thread t owns qp = qp0+t; 16 lane-consecutive LDS reads
//          (conflict-free), 2-level +/-1 butterfly (per-level scale 2*S*S == 1).
//   store: 4 float4 rows per thread, contiguous 1KB wave stores (ideal
//          WRITE_SIZE, verified v5/v7/v8).

#define B_     8
#define CIN    256
#define G_     16
#define PLANE  9216   // 96*96
#define W_     96
#define OW     384
#define CHUNK  256               // qp positions staged per block
#define NCHUNK (PLANE / CHUNK)   // 36
#define NBLK   (B_ * G_ * NCHUNK)       // 4608
#define PER_XCD (NBLK / 8)              // 576 — exactly one batch b per XCD

typedef float f4 __attribute__((ext_vector_type(4)));

__global__ __launch_bounds__(256) void idwt2_fused_v9(const float* __restrict__ x,
                                                      float* __restrict__ out) {
    __shared__ f4 lds4[16][CHUNK / 4];  // [j][qp_local/4] = 16 KB

    // XCD-affine bijective swizzle: hardware dispatch round-robins blockIdx.x
    // across the 8 XCDs, so hw%8 == XCD id. Give XCD k the logical blocks
    // [k*576, (k+1)*576) -> one full batch b per XCD, swept in order.
    const int hw  = blockIdx.x;
    const int bid = (hw % 8) * PER_XCD + (hw / 8);

    const int chunk = bid % NCHUNK;
    const int t1    = bid / NCHUNK;
    const int g     = t1 % G_;
    const int b     = t1 / G_;
    const int qp0   = chunk * CHUNK;

    const int t    = threadIdx.x;
    const int w    = t >> 6;   // wave id 0..3
    const int lane = t & 63;

    // ---- Load phase: 4 x global_load_dwordx4 per wave, each a contiguous 1KB run.
    // Wave w loads channel-taps j = 4w..4w+3; ch = g + 16j.
    const float* xbase = x + (size_t)b * CIN * PLANE + (size_t)qp0 + 4 * (size_t)lane;
#pragma unroll
    for (int l = 0; l < 4; ++l) {
        const int j  = 4 * w + l;          // 0..15
        const int ch = g + 16 * j;
        lds4[j][lane] = *reinterpret_cast<const f4*>(xbase + (size_t)ch * PLANE);
    }
    __syncthreads();

    // ---- Compute phase: thread t owns qp = qp0 + t.
    const float* ldsf = reinterpret_cast<const float*>(lds4);
    float vv[16];
#pragma unroll
    for (int j = 0; j < 16; ++j) {
        vv[j] = ldsf[j * CHUNK + t];       // lane-consecutive -> bank-conflict-free
    }

    // Level 1 (inner butterfly): v[k][m] = vv[k + 4m]
    float tt[4][2][2];
#pragma unroll
    for (int k = 0; k < 4; ++k) {
        float u0 = vv[k + 0] + vv[k + 4];
        float u1 = vv[k + 0] - vv[k + 4];
        float u2 = vv[k + 8] + vv[k + 12];
        float u3 = vv[k + 8] - vv[k + 12];
        tt[k][0][0] = u0 + u2;
        tt[k][0][1] = u0 - u2;
        tt[k][1][0] = u1 + u3;
        tt[k][1][1] = u1 - u3;
    }

    // Level 2 (outer butterfly) -> 4x4 output tile
    float rowv[4][4];
#pragma unroll
    for (int dh = 0; dh < 2; ++dh) {
#pragma unroll
        for (int dw = 0; dw < 2; ++dw) {
            float a0 = tt[0][dh][dw] + tt[1][dh][dw];
            float a1 = tt[0][dh][dw] - tt[1][dh][dw];
            float a2 = tt[2][dh][dw] + tt[3][dh][dw];
            float a3 = tt[2][dh][dw] - tt[3][dh][dw];
            rowv[2 * dh + 0][2 * dw + 0] = a0 + a2;
            rowv[2 * dh + 0][2 * dw + 1] = a0 - a2;
            rowv[2 * dh + 1][2 * dw + 0] = a1 + a3;
            rowv[2 * dh + 1][2 * dw + 1] = a1 - a3;
        }
    }

    // ---- Store phase: 4 rows of float4; lanes have consecutive qp -> contiguous
    // 1KB wave stores (2 runs max at the 96-wide row wrap).
    const int qp = qp0 + t;
    const int p  = qp / W_;
    const int q  = qp % W_;
    float* obase = out + ((size_t)(b * G_ + g) * OW + 4 * (size_t)p) * OW + 4 * (size_t)q;
#pragma unroll
    for (int r = 0; r < 4; ++r) {
        f4 s;
        s.x = rowv[r][0];
        s.y = rowv[r][1];
        s.z = rowv[r][2];
        s.w = rowv[r][3];
        *reinterpret_cast<f4*>(obase + (size_t)r * OW) = s;
    }
}

extern "C" void kernel_launch(void* const* d_in, const int* in_sizes, int n_in,
                              void* d_out, int out_size, void* d_ws, size_t ws_size,
                              hipStream_t stream) {
    const float* x = (const float*)d_in[0];
    float* out = (float*)d_out;
    idwt2_fused_v9<<<NBLK, 256, 0, stream>>>(x, out);  // 4608 blocks x 256 threads
}